// Round 1
// 541.025 us; speedup vs baseline: 1.1227x; 1.1227x over previous
//
#include <hip/hip_runtime.h>

typedef unsigned short ushort_t;
typedef unsigned long long u64;

#define B_ 8
#define L_ 2048
#define ROWS_ (B_ * L_)
#define IN_DIM_ 1024
#define D_ 64
#define DH_ 32
#define LN_EPS 1e-5f

using bf16x8 = __attribute__((ext_vector_type(8))) __bf16;
using f32x4  = __attribute__((ext_vector_type(4))) float;

__device__ __forceinline__ ushort_t f2bf(float x) {
  unsigned u = __float_as_uint(x);
  u += 0x7FFFu + ((u >> 16) & 1u);          // RNE bf16
  return (ushort_t)(u >> 16);
}
__device__ __forceinline__ float bf2f(ushort_t h) {
  return __uint_as_float(((unsigned)h) << 16);
}

// ---------------------------------------------------------------------------
// K1: fused MLP: LN(1024) -> mm 1024x64 + leaky -> LN(64) -> mm 64x64 + leaky
//     -> LN(64). Writes h (f32) and bf16 hi/lo split copies for MFMA stats.
// block=256, 8 rows/block.
// ---------------------------------------------------------------------------
__global__ __launch_bounds__(256) void k_mlp(
    const float* __restrict__ xin,
    const float* __restrict__ lnin_g, const float* __restrict__ lnin_b,
    const float* __restrict__ w_in, const float* __restrict__ b_in,
    const float* __restrict__ lnh1_g, const float* __restrict__ lnh1_b,
    const float* __restrict__ w_h, const float* __restrict__ b_h,
    const float* __restrict__ lnh2_g, const float* __restrict__ lnh2_b,
    float* __restrict__ hout, ushort_t* __restrict__ hhi, ushort_t* __restrict__ hlo)
{
  __shared__ float xln[8][IN_DIM_];
  __shared__ float part[4][8][D_];
  __shared__ float ybuf[8][D_];

  const int t = threadIdx.x;
  const int rowbase = blockIdx.x * 8;

  { // load + LN(1024): 32 threads per row
    const int g = t >> 5, l32 = t & 31;
    const float* xr = xin + (size_t)(rowbase + g) * IN_DIM_;
    float4 v[8];
    float s = 0.f, ss = 0.f;
#pragma unroll
    for (int it = 0; it < 8; ++it) {
      v[it] = *(const float4*)(xr + l32 * 4 + it * 128);
      s  += v[it].x + v[it].y + v[it].z + v[it].w;
      ss += v[it].x*v[it].x + v[it].y*v[it].y + v[it].z*v[it].z + v[it].w*v[it].w;
    }
#pragma unroll
    for (int off = 16; off >= 1; off >>= 1) { s += __shfl_xor(s, off); ss += __shfl_xor(ss, off); }
    const float mean = s * (1.f / IN_DIM_);
    const float var  = ss * (1.f / IN_DIM_) - mean * mean;
    const float rs   = rsqrtf(var + LN_EPS);
#pragma unroll
    for (int it = 0; it < 8; ++it) {
      const int idx = l32 * 4 + it * 128;
      float4 gv = *(const float4*)(lnin_g + idx);
      float4 bv = *(const float4*)(lnin_b + idx);
      xln[g][idx + 0] = (v[it].x - mean) * rs * gv.x + bv.x;
      xln[g][idx + 1] = (v[it].y - mean) * rs * gv.y + bv.y;
      xln[g][idx + 2] = (v[it].z - mean) * rs * gv.z + bv.z;
      xln[g][idx + 3] = (v[it].w - mean) * rs * gv.w + bv.w;
    }
  }
  __syncthreads();

  const int o = t & 63, kg = t >> 6;
  { // mm1: thread = (out col o, k-quarter kg), 8 rows at once
    float acc[8];
#pragma unroll
    for (int r = 0; r < 8; ++r) acc[r] = 0.f;
    const float* wp = w_in + (size_t)kg * 256 * D_ + o;
    const int kb = kg * 256;
    for (int k = 0; k < 256; ++k) {
      const float wv = wp[(size_t)k * D_];
#pragma unroll
      for (int r = 0; r < 8; ++r) acc[r] += xln[r][kb + k] * wv;
    }
#pragma unroll
    for (int r = 0; r < 8; ++r) part[kg][r][o] = acc[r];
  }
  __syncthreads();

  // reduce + bias + leaky + LN(64); wave kg owns rows kg and kg+4
#pragma unroll
  for (int rr = 0; rr < 2; ++rr) {
    const int r = kg + rr * 4;
    float a = part[0][r][o] + part[1][r][o] + part[2][r][o] + part[3][r][o] + b_in[o];
    a = a > 0.f ? a : 0.01f * a;
    float s1 = a, s2 = a * a;
#pragma unroll
    for (int off = 32; off >= 1; off >>= 1) { s1 += __shfl_xor(s1, off); s2 += __shfl_xor(s2, off); }
    const float mn = s1 * (1.f / 64), vr = s2 * (1.f / 64) - mn * mn;
    const float rs2 = rsqrtf(vr + LN_EPS);
    ybuf[r][o] = (a - mn) * rs2 * lnh1_g[o] + lnh1_b[o];
  }
  __syncthreads();

  // mm2 + bias + leaky + LN(64) + writeback (f32 + bf16 hi/lo)
#pragma unroll
  for (int rr = 0; rr < 2; ++rr) {
    const int r = kg + rr * 4;
    float a = 0.f;
#pragma unroll 8
    for (int k = 0; k < 64; ++k) a += ybuf[r][k] * w_h[k * D_ + o];
    a += b_h[o];
    a = a > 0.f ? a : 0.01f * a;
    float s1 = a, s2 = a * a;
#pragma unroll
    for (int off = 32; off >= 1; off >>= 1) { s1 += __shfl_xor(s1, off); s2 += __shfl_xor(s2, off); }
    const float mn = s1 * (1.f / 64), vr = s2 * (1.f / 64) - mn * mn;
    const float rs2 = rsqrtf(vr + LN_EPS);
    const float outv = (a - mn) * rs2 * lnh2_g[o] + lnh2_b[o];
    const size_t row = rowbase + r;
    hout[row * D_ + o] = outv;
    const ushort_t hb = f2bf(outv);
    hhi[row * D_ + o] = hb;
    hlo[row * D_ + o] = f2bf(outv - bf2f(hb));
  }
}

// ---------------------------------------------------------------------------
// K2: exact top-32 smallest dist per row (== top-32 dw for masks in {0,1}),
// stable-index tie-break to match jnp.argsort. Wave per row, 4 rows/block.
// Histogram-select -> ~34 candidates -> bitonic sort of packed keys.
//
// Atomic-contention fix: ~87.5% of uniform [0,1) values clamp to bin 255
// (bins cover [0,0.125)); same-address LDS atomicAdd serializes lane-by-lane
// and was 28.5M conflict cycles. Bin-255 hits are now counted in a per-lane
// register, wave-reduced via shfl, and written once by lane 0 -- the prefix
// scan only needs hist[255] exact, not atomic. Only ~12.5% of values (spread
// over 255 bins) still use atomicAdd. Loads vectorized to float4; element
// index re-derived as (k>>2)*256 + lane*4 + (k&3) so (value,index) keys are
// bit-identical to before.
// ---------------------------------------------------------------------------
#define BINS_ 256
#define CAP_ 64

__global__ __launch_bounds__(256) void k_topk(
    const float* __restrict__ dist,
    const float* __restrict__ masks,
    int* __restrict__ nbr)
{
  __shared__ unsigned hist[4][BINS_];
  __shared__ u64 cand[4][CAP_];
  __shared__ unsigned cnt[4];

  const int t = threadIdx.x, w = t >> 6, lane = t & 63;
  const int rowid = blockIdx.x * 4 + w;
  const int b = rowid >> 11;
  const float* dr = dist + (size_t)rowid * L_;
  const float* mrow = masks + (size_t)b * L_;

#pragma unroll
  for (int ii = 0; ii < BINS_ / 64; ++ii) hist[w][lane + ii * 64] = 0u;
  if (lane == 0) cnt[w] = 0u;
  __syncthreads();

  // element k (0..31) lives at j = (k>>2)*256 + lane*4 + (k&3)
  float vv[32];
  unsigned c255 = 0;
#pragma unroll
  for (int it = 0; it < 8; ++it) {
    const int j0 = it * 256 + lane * 4;
    const float4 v4 = *(const float4*)(dr + j0);
    const float4 m4 = *(const float4*)(mrow + j0);
    float e[4] = {v4.x, v4.y, v4.z, v4.w};
    const float mk[4] = {m4.x, m4.y, m4.z, m4.w};
#pragma unroll
    for (int q = 0; q < 4; ++q) {
      float v = (mk[q] > 0.f) ? e[q] : 1.0e30f;   // masked -> worst rank
      vv[it * 4 + q] = v;
      const int bin = (int)fminf(v * 2048.0f, 255.0f);  // 256 bins over [0,0.125)+clamp
      if (bin < 255) atomicAdd(&hist[w][bin], 1u);
      else ++c255;
    }
  }
  // hot bin (255) counted without atomics: wave-reduce + single store
#pragma unroll
  for (int off = 32; off >= 1; off >>= 1) c255 += __shfl_xor(c255, off);
  if (lane == 0) hist[w][255] = c255;
  __syncthreads();

  // prefix-scan histogram, find first bin with cum >= 32
  const unsigned b0 = hist[w][lane * 4 + 0];
  const unsigned b1 = hist[w][lane * 4 + 1];
  const unsigned b2 = hist[w][lane * 4 + 2];
  const unsigned b3 = hist[w][lane * 4 + 3];
  const unsigned tot = b0 + b1 + b2 + b3;
  unsigned run = tot;
#pragma unroll
  for (int off = 1; off < 64; off <<= 1) {
    const unsigned o2 = __shfl_up(run, off);
    if (lane >= off) run += o2;
  }
  const unsigned before = run - tot;
  const unsigned c0 = before + b0, c1 = c0 + b1, c2 = c1 + b2, c3 = c2 + b3;
  const int lk = (c0 >= 32u) ? 0 : (c1 >= 32u) ? 1 : (c2 >= 32u) ? 2 : (c3 >= 32u) ? 3 : -1;
  const u64 ball = __ballot(lk >= 0);
  const int fl = (int)__builtin_ctzll(ball);
  const int ksel = __shfl(lk, fl) + fl * 4;

  // compact candidates (bin <= ksel); count is exact even past CAP_
#pragma unroll
  for (int k = 0; k < 32; ++k) {
    const int bin = (int)fminf(vv[k] * 2048.0f, 255.0f);
    if (bin <= ksel) {
      const unsigned pos = atomicAdd(&cnt[w], 1u);
      if (pos < CAP_)
        cand[w][pos] = ((u64)__float_as_uint(vv[k]) << 11)
                     | (u64)(unsigned)((k >> 2) * 256 + lane * 4 + (k & 3));
    }
  }
  __syncthreads();

  const unsigned C = cnt[w];
  if (C <= CAP_) {
    // bitonic sort 64 keys across the wave, take 32 smallest
    u64 kk = (lane < (int)C) ? cand[w][lane] : 0xFFFFFFFFFFFFFFFFull;
#pragma unroll
    for (int kstep = 2; kstep <= 64; kstep <<= 1) {
#pragma unroll
      for (int jstep = kstep >> 1; jstep > 0; jstep >>= 1) {
        const u64 other = __shfl_xor(kk, jstep);
        const bool up = ((lane & kstep) == 0);
        const bool lower = ((lane & jstep) == 0);
        const u64 mnv = kk < other ? kk : other;
        const u64 mxv = kk < other ? other : kk;
        kk = (lower == up) ? mnv : mxv;
      }
    }
    if (lane < 32) nbr[(size_t)rowid * 32 + lane] = (int)(kk & 0x7FFull);
  } else {
    // exact fallback (statistically never taken): 32x extract-min
    int outk = 0;
#pragma unroll 1
    for (int it = 0; it < 32; ++it) {
      float bv = vv[0]; int bk = 0;
#pragma unroll
      for (int k = 1; k < 32; ++k) { if (vv[k] < bv) { bv = vv[k]; bk = k; } }
      const u64 mykey = ((u64)__float_as_uint(bv) << 11)
                      | (u64)(unsigned)((bk >> 2) * 256 + lane * 4 + (bk & 3));
      u64 best = mykey;
#pragma unroll
      for (int off = 32; off >= 1; off >>= 1) {
        const u64 o3 = __shfl_xor(best, off);
        if (o3 < best) best = o3;
      }
      if (lane == it) outk = (int)(best & 0x7FFull);
      const bool win = (best == mykey);
#pragma unroll
      for (int k = 0; k < 32; ++k) if (win && (k == bk)) vv[k] = 3.0e38f;
    }
    if (lane < 32) nbr[(size_t)rowid * 32 + lane] = outk;
  }
}

// ---------------------------------------------------------------------------
// K3a: full-row softmax stats (m, Z) of S = h_head @ h_head^T (+add_mask),
// split-bf16 MFMA (hi*hi + hi*lo + lo*hi), online max/sumexp.
// block=256: wave=16 rows; grid = (b,h) x 32 row-tiles x 4 J-chunks.
// Writes partial (m,z) per chunk; merged in K3b.
// ---------------------------------------------------------------------------
__global__ __launch_bounds__(256) void k_stats(
    const ushort_t* __restrict__ hhi, const ushort_t* __restrict__ hlo,
    const float* __restrict__ masks,
    float2* __restrict__ mz)
{
  const int t = threadIdx.x, w = t >> 6, lane = t & 63;
  const int bid = blockIdx.x;
  const int bh = bid & 15;
  const int rtile = (bid >> 4) & 31;
  const int chunk = bid >> 9;
  const int b = bh >> 1, head = bh & 1;
  const int rbase = rtile * 64 + w * 16;
  const int mrow = lane & 15, quad = lane >> 4;

  // A-frag: lane holds A[m=lane&15][k=quad*8..+8] (8 contiguous bf16 = 16B)
  const size_t aoff = (size_t)(b * L_ + rbase + mrow) * D_ + head * DH_ + quad * 8;
  const bf16x8 a_hi = *(const bf16x8*)(hhi + aoff);
  const bf16x8 a_lo = *(const bf16x8*)(hlo + aoff);

  float mm[4], zz[4];
#pragma unroll
  for (int r = 0; r < 4; ++r) { mm[r] = -3.0e38f; zz[r] = 0.f; }

  for (int jt = 0; jt < 8; ++jt) {
    const int jbase = chunk * 512 + jt * 64;
    f32x4 cc[4];
    float am[4];
#pragma unroll
    for (int nt = 0; nt < 4; ++nt) {
      const int j = jbase + nt * 16 + mrow;
      const size_t boff = (size_t)(b * L_ + j) * D_ + head * DH_ + quad * 8;
      const bf16x8 b_hi = *(const bf16x8*)(hhi + boff);
      const bf16x8 b_lo = *(const bf16x8*)(hlo + boff);
      f32x4 c = {0.f, 0.f, 0.f, 0.f};
      c = __builtin_amdgcn_mfma_f32_16x16x32_bf16(a_hi, b_hi, c, 0, 0, 0);
      c = __builtin_amdgcn_mfma_f32_16x16x32_bf16(a_hi, b_lo, c, 0, 0, 0);
      c = __builtin_amdgcn_mfma_f32_16x16x32_bf16(a_lo, b_hi, c, 0, 0, 0);
      cc[nt] = c;
      am[nt] = (1.0f - masks[b * L_ + j]) * -10000.0f;  // C col = lane&15 too
    }
    // online stats; lane's C rows = rbase + quad*4 + r, col = nt*16 + mrow
#pragma unroll
    for (int r = 0; r < 4; ++r) {
      const float s0 = cc[0][r] + am[0];
      const float s1 = cc[1][r] + am[1];
      const float s2 = cc[2][r] + am[2];
      const float s3 = cc[3][r] + am[3];
      const float tm = fmaxf(fmaxf(s0, s1), fmaxf(s2, s3));
      const float mn = fmaxf(mm[r], tm);
      zz[r] = zz[r] * __expf(mm[r] - mn)
            + __expf(s0 - mn) + __expf(s1 - mn) + __expf(s2 - mn) + __expf(s3 - mn);
      mm[r] = mn;
    }
  }
  // combine across the 16 lanes (cols) sharing each row
#pragma unroll
  for (int off = 1; off < 16; off <<= 1) {
#pragma unroll
    for (int r = 0; r < 4; ++r) {
      const float om = __shfl_xor(mm[r], off);
      const float oz = __shfl_xor(zz[r], off);
      const float mn = fmaxf(mm[r], om);
      zz[r] = zz[r] * __expf(mm[r] - mn) + oz * __expf(om - mn);
      mm[r] = mn;
    }
  }
  if (mrow == 0) {
#pragma unroll
    for (int r = 0; r < 4; ++r) {
      const int row = rbase + quad * 4 + r;
      mz[((size_t)(bh * L_ + row)) * 4 + chunk] = make_float2(mm[r], zz[r]);
    }
  }
}

// ---------------------------------------------------------------------------
// K3b: per row: merge (m,Z) chunks; gather 32 neighbors; fp32 scores;
// out = sum e_j h_j / (sum e_j + 1e-5*Z); LN(64); either write next-h (+bf16
// hi/lo) or final projection y = LN(out) @ w_out + b_out. Wave per row.
// ---------------------------------------------------------------------------
__global__ __launch_bounds__(256) void k_gather(
    const float* __restrict__ h,
    const int* __restrict__ nbr,
    const float2* __restrict__ mz,
    const float* __restrict__ masks,
    const float* __restrict__ lng, const float* __restrict__ lnb,
    const int last,
    float* __restrict__ hn, ushort_t* __restrict__ hnhi, ushort_t* __restrict__ hnlo,
    const float* __restrict__ w_out, const float* __restrict__ b_out,
    float* __restrict__ y)
{
  const int t = threadIdx.x, w = t >> 6, d = t & 63;
  const int row = blockIdx.x * 4 + w;
  const int b = row >> 11;
  const int i = row & (L_ - 1);
  const int head = d >> 5;
  const int bh = b * 2 + head;

  float m_h = -3.0e38f, Z_h = 0.f;
#pragma unroll
  for (int c = 0; c < 4; ++c) {
    const float2 p = mz[((size_t)(bh * L_ + i)) * 4 + c];
    const float mn = fmaxf(m_h, p.x);
    Z_h = Z_h * __expf(m_h - mn) + p.y * __expf(p.x - mn);
    m_h = mn;
  }

  const float xi = h[(size_t)row * D_ + d];
  int myn = 0;
  if (d < 32) myn = nbr[(size_t)row * 32 + d];

  float num = 0.f, den = 0.f;
#pragma unroll 4
  for (int r = 0; r < 32; ++r) {
    const int j = __shfl(myn, r);
    const float vj = h[((size_t)(b * L_ + j)) * D_ + d];
    float p = xi * vj;
#pragma unroll
    for (int off = 16; off >= 1; off >>= 1) p += __shfl_xor(p, off);  // per-head dot32
    const float am = (1.0f - masks[b * L_ + j]) * -10000.0f;
    const float e = __expf(p + am - m_h);
    num += e * vj;
    den += e;
  }
  const float outv = num / (den + 1e-5f * Z_h);

  float s1 = outv, s2 = outv * outv;
#pragma unroll
  for (int off = 32; off >= 1; off >>= 1) { s1 += __shfl_xor(s1, off); s2 += __shfl_xor(s2, off); }
  const float mn = s1 * (1.f / 64), vr = s2 * (1.f / 64) - mn * mn;
  const float rs = rsqrtf(vr + LN_EPS);
  const float xr = (outv - mn) * rs * lng[d] + lnb[d];

  if (!last) {
    hn[(size_t)row * D_ + d] = xr;
    const ushort_t hb = f2bf(xr);
    hnhi[(size_t)row * D_ + d] = hb;
    hnlo[(size_t)row * D_ + d] = f2bf(xr - bf2f(hb));
  } else {
    float yv = xr * w_out[d];
#pragma unroll
    for (int off = 32; off >= 1; off >>= 1) yv += __shfl_xor(yv, off);
    if (d == 0) y[row] = yv + b_out[0];
  }
}

// ---------------------------------------------------------------------------
extern "C" void kernel_launch(void* const* d_in, const int* in_sizes, int n_in,
                              void* d_out, int out_size, void* d_ws, size_t ws_size,
                              hipStream_t stream)
{
  const float* xin    = (const float*)d_in[0];
  // d_in[1] protein_edge_features: unused by the reference
  const float* dist   = (const float*)d_in[2];
  const float* masks  = (const float*)d_in[3];
  const float* lnin_g = (const float*)d_in[4];
  const float* lnin_b = (const float*)d_in[5];
  const float* w_in   = (const float*)d_in[6];
  const float* b_in   = (const float*)d_in[7];
  const float* lnh1_g = (const float*)d_in[8];
  const float* lnh1_b = (const float*)d_in[9];
  const float* w_h    = (const float*)d_in[10];
  const float* b_h    = (const float*)d_in[11];
  const float* lnh2_g = (const float*)d_in[12];
  const float* lnh2_b = (const float*)d_in[13];
  const float* lna0_g = (const float*)d_in[14];
  const float* lna0_b = (const float*)d_in[15];
  const float* lna1_g = (const float*)d_in[16];
  const float* lna1_b = (const float*)d_in[17];
  const float* w_out  = (const float*)d_in[18];
  const float* b_out  = (const float*)d_in[19];
  float* y = (float*)d_out;

  char* p = (char*)d_ws;
  float*    h1   = (float*)p;    p += (size_t)ROWS_ * D_ * 4;
  float*    h2   = (float*)p;    p += (size_t)ROWS_ * D_ * 4;
  ushort_t* h1hi = (ushort_t*)p; p += (size_t)ROWS_ * D_ * 2;
  ushort_t* h1lo = (ushort_t*)p; p += (size_t)ROWS_ * D_ * 2;
  ushort_t* h2hi = (ushort_t*)p; p += (size_t)ROWS_ * D_ * 2;
  ushort_t* h2lo = (ushort_t*)p; p += (size_t)ROWS_ * D_ * 2;
  int*      nbr  = (int*)p;      p += (size_t)ROWS_ * 32 * 4;
  float2*   mz   = (float2*)p;   p += (size_t)B_ * 2 * L_ * 4 * sizeof(float2);

  k_mlp<<<ROWS_ / 8, 256, 0, stream>>>(xin, lnin_g, lnin_b, w_in, b_in,
                                       lnh1_g, lnh1_b, w_h, b_h, lnh2_g, lnh2_b,
                                       h1, h1hi, h1lo);
  k_topk<<<ROWS_ / 4, 256, 0, stream>>>(dist, masks, nbr);
  k_stats<<<2048, 256, 0, stream>>>(h1hi, h1lo, masks, mz);
  k_gather<<<ROWS_ / 4, 256, 0, stream>>>(h1, nbr, mz, masks, lna0_g, lna0_b, 0,
                                          h2, h2hi, h2lo, w_out, b_out, y);
  k_stats<<<2048, 256, 0, stream>>>(h2hi, h2lo, masks, mz);
  k_gather<<<ROWS_ / 4, 256, 0, stream>>>(h2, nbr, mz, masks, lna1_g, lna1_b, 1,
                                          h2, h2hi, h2lo, w_out, b_out, y);
}

// Round 4
// 537.604 us; speedup vs baseline: 1.1299x; 1.0064x over previous
//
#include <hip/hip_runtime.h>

typedef unsigned short ushort_t;
typedef unsigned long long u64;

#define B_ 8
#define L_ 2048
#define ROWS_ (B_ * L_)
#define IN_DIM_ 1024
#define D_ 64
#define DH_ 32
#define LN_EPS 1e-5f

using bf16x8 = __attribute__((ext_vector_type(8))) __bf16;
using f32x4  = __attribute__((ext_vector_type(4))) float;

__device__ __forceinline__ ushort_t f2bf(float x) {
  unsigned u = __float_as_uint(x);
  u += 0x7FFFu + ((u >> 16) & 1u);          // RNE bf16
  return (ushort_t)(u >> 16);
}
__device__ __forceinline__ float bf2f(ushort_t h) {
  return __uint_as_float(((unsigned)h) << 16);
}

// ---------------------------------------------------------------------------
// K1: fused MLP: LN(1024) -> mm 1024x64 + leaky -> LN(64) -> mm 64x64 + leaky
//     -> LN(64). Exact fp32 math (MFMA-split variants failed accuracy: the
//     downstream 2x attention amplifies h errors ~2e4x, so mm1 needs fp32).
// block=256, 8 rows/block. mm1/mm2 inner loops use float4 LDS broadcast
// reads (4x fewer LDS instructions, identical fma accumulation order).
// ---------------------------------------------------------------------------
__global__ __launch_bounds__(256) void k_mlp(
    const float* __restrict__ xin,
    const float* __restrict__ lnin_g, const float* __restrict__ lnin_b,
    const float* __restrict__ w_in, const float* __restrict__ b_in,
    const float* __restrict__ lnh1_g, const float* __restrict__ lnh1_b,
    const float* __restrict__ w_h, const float* __restrict__ b_h,
    const float* __restrict__ lnh2_g, const float* __restrict__ lnh2_b,
    float* __restrict__ hout, ushort_t* __restrict__ hhi, ushort_t* __restrict__ hlo)
{
  __shared__ __align__(16) float xln[8][IN_DIM_];
  __shared__ float part[4][8][D_];
  __shared__ __align__(16) float ybuf[8][D_];

  const int t = threadIdx.x;
  const int rowbase = blockIdx.x * 8;

  { // load + LN(1024): 32 threads per row
    const int g = t >> 5, l32 = t & 31;
    const float* xr = xin + (size_t)(rowbase + g) * IN_DIM_;
    float4 v[8];
    float s = 0.f, ss = 0.f;
#pragma unroll
    for (int it = 0; it < 8; ++it) {
      v[it] = *(const float4*)(xr + l32 * 4 + it * 128);
      s  += v[it].x + v[it].y + v[it].z + v[it].w;
      ss += v[it].x*v[it].x + v[it].y*v[it].y + v[it].z*v[it].z + v[it].w*v[it].w;
    }
#pragma unroll
    for (int off = 16; off >= 1; off >>= 1) { s += __shfl_xor(s, off); ss += __shfl_xor(ss, off); }
    const float mean = s * (1.f / IN_DIM_);
    const float var  = ss * (1.f / IN_DIM_) - mean * mean;
    const float rs   = rsqrtf(var + LN_EPS);
#pragma unroll
    for (int it = 0; it < 8; ++it) {
      const int idx = l32 * 4 + it * 128;
      float4 gv = *(const float4*)(lnin_g + idx);
      float4 bv = *(const float4*)(lnin_b + idx);
      xln[g][idx + 0] = (v[it].x - mean) * rs * gv.x + bv.x;
      xln[g][idx + 1] = (v[it].y - mean) * rs * gv.y + bv.y;
      xln[g][idx + 2] = (v[it].z - mean) * rs * gv.z + bv.z;
      xln[g][idx + 3] = (v[it].w - mean) * rs * gv.w + bv.w;
    }
  }
  __syncthreads();

  const int o = t & 63, kg = t >> 6;
  { // mm1: thread = (out col o, k-quarter kg), 8 rows at once.
    // float4 xln reads (broadcast across the wave, conflict-free); fma order
    // per acc[r] is k-ascending, identical to the scalar version.
    float acc[8];
#pragma unroll
    for (int r = 0; r < 8; ++r) acc[r] = 0.f;
    const float* wp = w_in + (size_t)kg * 256 * D_ + o;
    const int kb = kg * 256;
#pragma unroll 2
    for (int k4 = 0; k4 < 64; ++k4) {
      const int k = k4 * 4;
      const float w0 = wp[(size_t)(k + 0) * D_];
      const float w1 = wp[(size_t)(k + 1) * D_];
      const float w2 = wp[(size_t)(k + 2) * D_];
      const float w3 = wp[(size_t)(k + 3) * D_];
      float4 xv[8];
#pragma unroll
      for (int r = 0; r < 8; ++r) xv[r] = *(const float4*)&xln[r][kb + k];
#pragma unroll
      for (int r = 0; r < 8; ++r) {
        acc[r] += xv[r].x * w0;
        acc[r] += xv[r].y * w1;
        acc[r] += xv[r].z * w2;
        acc[r] += xv[r].w * w3;
      }
    }
#pragma unroll
    for (int r = 0; r < 8; ++r) part[kg][r][o] = acc[r];
  }
  __syncthreads();

  // reduce + bias + leaky + LN(64); wave kg owns rows kg and kg+4
#pragma unroll
  for (int rr = 0; rr < 2; ++rr) {
    const int r = kg + rr * 4;
    float a = part[0][r][o] + part[1][r][o] + part[2][r][o] + part[3][r][o] + b_in[o];
    a = a > 0.f ? a : 0.01f * a;
    float s1 = a, s2 = a * a;
#pragma unroll
    for (int off = 32; off >= 1; off >>= 1) { s1 += __shfl_xor(s1, off); s2 += __shfl_xor(s2, off); }
    const float mn = s1 * (1.f / 64), vr = s2 * (1.f / 64) - mn * mn;
    const float rs2 = rsqrtf(vr + LN_EPS);
    ybuf[r][o] = (a - mn) * rs2 * lnh1_g[o] + lnh1_b[o];
  }
  __syncthreads();

  // mm2 + bias + leaky + LN(64) + writeback (f32 + bf16 hi/lo)
#pragma unroll
  for (int rr = 0; rr < 2; ++rr) {
    const int r = kg + rr * 4;
    float a = 0.f;
#pragma unroll
    for (int k4 = 0; k4 < 16; ++k4) {
      const int k = k4 * 4;
      const float4 yv = *(const float4*)&ybuf[r][k];
      a += yv.x * w_h[(size_t)(k + 0) * D_ + o];
      a += yv.y * w_h[(size_t)(k + 1) * D_ + o];
      a += yv.z * w_h[(size_t)(k + 2) * D_ + o];
      a += yv.w * w_h[(size_t)(k + 3) * D_ + o];
    }
    a += b_h[o];
    a = a > 0.f ? a : 0.01f * a;
    float s1 = a, s2 = a * a;
#pragma unroll
    for (int off = 32; off >= 1; off >>= 1) { s1 += __shfl_xor(s1, off); s2 += __shfl_xor(s2, off); }
    const float mn = s1 * (1.f / 64), vr = s2 * (1.f / 64) - mn * mn;
    const float rs2 = rsqrtf(vr + LN_EPS);
    const float outv = (a - mn) * rs2 * lnh2_g[o] + lnh2_b[o];
    const size_t row = rowbase + r;
    hout[row * D_ + o] = outv;
    const ushort_t hb = f2bf(outv);
    hhi[row * D_ + o] = hb;
    hlo[row * D_ + o] = f2bf(outv - bf2f(hb));
  }
}

// ---------------------------------------------------------------------------
// K2: exact top-32 smallest dist per row, stable-index tie-break.
// Hot bin 255 (87.5% of uniform values) counted in registers, not atomics.
// ---------------------------------------------------------------------------
#define BINS_ 256
#define CAP_ 64

__global__ __launch_bounds__(256) void k_topk(
    const float* __restrict__ dist,
    const float* __restrict__ masks,
    int* __restrict__ nbr)
{
  __shared__ unsigned hist[4][BINS_];
  __shared__ u64 cand[4][CAP_];
  __shared__ unsigned cnt[4];

  const int t = threadIdx.x, w = t >> 6, lane = t & 63;
  const int rowid = blockIdx.x * 4 + w;
  const int b = rowid >> 11;
  const float* dr = dist + (size_t)rowid * L_;
  const float* mrow = masks + (size_t)b * L_;

#pragma unroll
  for (int ii = 0; ii < BINS_ / 64; ++ii) hist[w][lane + ii * 64] = 0u;
  if (lane == 0) cnt[w] = 0u;
  __syncthreads();

  // element k (0..31) lives at j = (k>>2)*256 + lane*4 + (k&3)
  float vv[32];
  unsigned c255 = 0;
#pragma unroll
  for (int it = 0; it < 8; ++it) {
    const int j0 = it * 256 + lane * 4;
    const float4 v4 = *(const float4*)(dr + j0);
    const float4 m4 = *(const float4*)(mrow + j0);
    float e[4] = {v4.x, v4.y, v4.z, v4.w};
    const float mk[4] = {m4.x, m4.y, m4.z, m4.w};
#pragma unroll
    for (int q = 0; q < 4; ++q) {
      float v = (mk[q] > 0.f) ? e[q] : 1.0e30f;   // masked -> worst rank
      vv[it * 4 + q] = v;
      const int bin = (int)fminf(v * 2048.0f, 255.0f);  // 256 bins over [0,0.125)+clamp
      if (bin < 255) atomicAdd(&hist[w][bin], 1u);
      else ++c255;
    }
  }
#pragma unroll
  for (int off = 32; off >= 1; off >>= 1) c255 += __shfl_xor(c255, off);
  if (lane == 0) hist[w][255] = c255;
  __syncthreads();

  // prefix-scan histogram, find first bin with cum >= 32
  const unsigned b0 = hist[w][lane * 4 + 0];
  const unsigned b1 = hist[w][lane * 4 + 1];
  const unsigned b2 = hist[w][lane * 4 + 2];
  const unsigned b3 = hist[w][lane * 4 + 3];
  const unsigned tot = b0 + b1 + b2 + b3;
  unsigned run = tot;
#pragma unroll
  for (int off = 1; off < 64; off <<= 1) {
    const unsigned o2 = __shfl_up(run, off);
    if (lane >= off) run += o2;
  }
  const unsigned before = run - tot;
  const unsigned c0 = before + b0, c1 = c0 + b1, c2 = c1 + b2, c3 = c2 + b3;
  const int lk = (c0 >= 32u) ? 0 : (c1 >= 32u) ? 1 : (c2 >= 32u) ? 2 : (c3 >= 32u) ? 3 : -1;
  const u64 ball = __ballot(lk >= 0);
  const int fl = (int)__builtin_ctzll(ball);
  const int ksel = __shfl(lk, fl) + fl * 4;

  // compact candidates (bin <= ksel); count is exact even past CAP_
#pragma unroll
  for (int k = 0; k < 32; ++k) {
    const int bin = (int)fminf(vv[k] * 2048.0f, 255.0f);
    if (bin <= ksel) {
      const unsigned pos = atomicAdd(&cnt[w], 1u);
      if (pos < CAP_)
        cand[w][pos] = ((u64)__float_as_uint(vv[k]) << 11)
                     | (u64)(unsigned)((k >> 2) * 256 + lane * 4 + (k & 3));
    }
  }
  __syncthreads();

  const unsigned C = cnt[w];
  if (C <= CAP_) {
    u64 kk = (lane < (int)C) ? cand[w][lane] : 0xFFFFFFFFFFFFFFFFull;
#pragma unroll
    for (int kstep = 2; kstep <= 64; kstep <<= 1) {
#pragma unroll
      for (int jstep = kstep >> 1; jstep > 0; jstep >>= 1) {
        const u64 other = __shfl_xor(kk, jstep);
        const bool up = ((lane & kstep) == 0);
        const bool lower = ((lane & jstep) == 0);
        const u64 mnv = kk < other ? kk : other;
        const u64 mxv = kk < other ? other : kk;
        kk = (lower == up) ? mnv : mxv;
      }
    }
    if (lane < 32) nbr[(size_t)rowid * 32 + lane] = (int)(kk & 0x7FFull);
  } else {
    // exact fallback (statistically never taken): 32x extract-min
    int outk = 0;
#pragma unroll 1
    for (int it = 0; it < 32; ++it) {
      float bv = vv[0]; int bk = 0;
#pragma unroll
      for (int k = 1; k < 32; ++k) { if (vv[k] < bv) { bv = vv[k]; bk = k; } }
      const u64 mykey = ((u64)__float_as_uint(bv) << 11)
                      | (u64)(unsigned)((bk >> 2) * 256 + lane * 4 + (bk & 3));
      u64 best = mykey;
#pragma unroll
      for (int off = 32; off >= 1; off >>= 1) {
        const u64 o3 = __shfl_xor(best, off);
        if (o3 < best) best = o3;
      }
      if (lane == it) outk = (int)(best & 0x7FFull);
      const bool win = (best == mykey);
#pragma unroll
      for (int k = 0; k < 32; ++k) if (win && (k == bk)) vv[k] = 3.0e38f;
    }
    if (lane < 32) nbr[(size_t)rowid * 32 + lane] = outk;
  }
}

// ---------------------------------------------------------------------------
// K3a: full-row softmax stats (m, Z) of S = h_head @ h_head^T (+add_mask),
// split-bf16 MFMA, online max/sumexp.
// ---------------------------------------------------------------------------
__global__ __launch_bounds__(256) void k_stats(
    const ushort_t* __restrict__ hhi, const ushort_t* __restrict__ hlo,
    const float* __restrict__ masks,
    float2* __restrict__ mz)
{
  const int t = threadIdx.x, w = t >> 6, lane = t & 63;
  const int bid = blockIdx.x;
  const int bh = bid & 15;
  const int rtile = (bid >> 4) & 31;
  const int chunk = bid >> 9;
  const int b = bh >> 1, head = bh & 1;
  const int rbase = rtile * 64 + w * 16;
  const int mrow = lane & 15, quad = lane >> 4;

  const size_t aoff = (size_t)(b * L_ + rbase + mrow) * D_ + head * DH_ + quad * 8;
  const bf16x8 a_hi = *(const bf16x8*)(hhi + aoff);
  const bf16x8 a_lo = *(const bf16x8*)(hlo + aoff);

  float mm[4], zz[4];
#pragma unroll
  for (int r = 0; r < 4; ++r) { mm[r] = -3.0e38f; zz[r] = 0.f; }

  for (int jt = 0; jt < 8; ++jt) {
    const int jbase = chunk * 512 + jt * 64;
    f32x4 cc[4];
    float am[4];
#pragma unroll
    for (int nt = 0; nt < 4; ++nt) {
      const int j = jbase + nt * 16 + mrow;
      const size_t boff = (size_t)(b * L_ + j) * D_ + head * DH_ + quad * 8;
      const bf16x8 b_hi = *(const bf16x8*)(hhi + boff);
      const bf16x8 b_lo = *(const bf16x8*)(hlo + boff);
      f32x4 c = {0.f, 0.f, 0.f, 0.f};
      c = __builtin_amdgcn_mfma_f32_16x16x32_bf16(a_hi, b_hi, c, 0, 0, 0);
      c = __builtin_amdgcn_mfma_f32_16x16x32_bf16(a_hi, b_lo, c, 0, 0, 0);
      c = __builtin_amdgcn_mfma_f32_16x16x32_bf16(a_lo, b_hi, c, 0, 0, 0);
      cc[nt] = c;
      am[nt] = (1.0f - masks[b * L_ + j]) * -10000.0f;
    }
#pragma unroll
    for (int r = 0; r < 4; ++r) {
      const float s0 = cc[0][r] + am[0];
      const float s1 = cc[1][r] + am[1];
      const float s2 = cc[2][r] + am[2];
      const float s3 = cc[3][r] + am[3];
      const float tm = fmaxf(fmaxf(s0, s1), fmaxf(s2, s3));
      const float mn = fmaxf(mm[r], tm);
      zz[r] = zz[r] * __expf(mm[r] - mn)
            + __expf(s0 - mn) + __expf(s1 - mn) + __expf(s2 - mn) + __expf(s3 - mn);
      mm[r] = mn;
    }
  }
#pragma unroll
  for (int off = 1; off < 16; off <<= 1) {
#pragma unroll
    for (int r = 0; r < 4; ++r) {
      const float om = __shfl_xor(mm[r], off);
      const float oz = __shfl_xor(zz[r], off);
      const float mn = fmaxf(mm[r], om);
      zz[r] = zz[r] * __expf(mm[r] - mn) + oz * __expf(om - mn);
      mm[r] = mn;
    }
  }
  if (mrow == 0) {
#pragma unroll
    for (int r = 0; r < 4; ++r) {
      const int row = rbase + quad * 4 + r;
      mz[((size_t)(bh * L_ + row)) * 4 + chunk] = make_float2(mm[r], zz[r]);
    }
  }
}

// ---------------------------------------------------------------------------
// K3b: per row: merge (m,Z) chunks; gather 32 neighbors; fp32 scores;
// out = sum e_j h_j / (sum e_j + 1e-5*Z); LN(64); write next-h or final y.
// ---------------------------------------------------------------------------
__global__ __launch_bounds__(256) void k_gather(
    const float* __restrict__ h,
    const int* __restrict__ nbr,
    const float2* __restrict__ mz,
    const float* __restrict__ masks,
    const float* __restrict__ lng, const float* __restrict__ lnb,
    const int last,
    float* __restrict__ hn, ushort_t* __restrict__ hnhi, ushort_t* __restrict__ hnlo,
    const float* __restrict__ w_out, const float* __restrict__ b_out,
    float* __restrict__ y)
{
  const int t = threadIdx.x, w = t >> 6, d = t & 63;
  const int row = blockIdx.x * 4 + w;
  const int b = row >> 11;
  const int i = row & (L_ - 1);
  const int head = d >> 5;
  const int bh = b * 2 + head;

  float m_h = -3.0e38f, Z_h = 0.f;
#pragma unroll
  for (int c = 0; c < 4; ++c) {
    const float2 p = mz[((size_t)(bh * L_ + i)) * 4 + c];
    const float mn = fmaxf(m_h, p.x);
    Z_h = Z_h * __expf(m_h - mn) + p.y * __expf(p.x - mn);
    m_h = mn;
  }

  const float xi = h[(size_t)row * D_ + d];
  int myn = 0;
  if (d < 32) myn = nbr[(size_t)row * 32 + d];

  float num = 0.f, den = 0.f;
#pragma unroll 4
  for (int r = 0; r < 32; ++r) {
    const int j = __shfl(myn, r);
    const float vj = h[((size_t)(b * L_ + j)) * D_ + d];
    float p = xi * vj;
#pragma unroll
    for (int off = 16; off >= 1; off >>= 1) p += __shfl_xor(p, off);  // per-head dot32
    const float am = (1.0f - masks[b * L_ + j]) * -10000.0f;
    const float e = __expf(p + am - m_h);
    num += e * vj;
    den += e;
  }
  const float outv = num / (den + 1e-5f * Z_h);

  float s1 = outv, s2 = outv * outv;
#pragma unroll
  for (int off = 32; off >= 1; off >>= 1) { s1 += __shfl_xor(s1, off); s2 += __shfl_xor(s2, off); }
  const float mn = s1 * (1.f / 64), vr = s2 * (1.f / 64) - mn * mn;
  const float rs = rsqrtf(vr + LN_EPS);
  const float xr = (outv - mn) * rs * lng[d] + lnb[d];

  if (!last) {
    hn[(size_t)row * D_ + d] = xr;
    const ushort_t hb = f2bf(xr);
    hnhi[(size_t)row * D_ + d] = hb;
    hnlo[(size_t)row * D_ + d] = f2bf(xr - bf2f(hb));
  } else {
    float yv = xr * w_out[d];
#pragma unroll
    for (int off = 32; off >= 1; off >>= 1) yv += __shfl_xor(yv, off);
    if (d == 0) y[row] = yv + b_out[0];
  }
}

// ---------------------------------------------------------------------------
extern "C" void kernel_launch(void* const* d_in, const int* in_sizes, int n_in,
                              void* d_out, int out_size, void* d_ws, size_t ws_size,
                              hipStream_t stream)
{
  const float* xin    = (const float*)d_in[0];
  // d_in[1] protein_edge_features: unused by the reference
  const float* dist   = (const float*)d_in[2];
  const float* masks  = (const float*)d_in[3];
  const float* lnin_g = (const float*)d_in[4];
  const float* lnin_b = (const float*)d_in[5];
  const float* w_in   = (const float*)d_in[6];
  const float* b_in   = (const float*)d_in[7];
  const float* lnh1_g = (const float*)d_in[8];
  const float* lnh1_b = (const float*)d_in[9];
  const float* w_h    = (const float*)d_in[10];
  const float* b_h    = (const float*)d_in[11];
  const float* lnh2_g = (const float*)d_in[12];
  const float* lnh2_b = (const float*)d_in[13];
  const float* lna0_g = (const float*)d_in[14];
  const float* lna0_b = (const float*)d_in[15];
  const float* lna1_g = (const float*)d_in[16];
  const float* lna1_b = (const float*)d_in[17];
  const float* w_out  = (const float*)d_in[18];
  const float* b_out  = (const float*)d_in[19];
  float* y = (float*)d_out;

  char* p = (char*)d_ws;
  float*    h1   = (float*)p;    p += (size_t)ROWS_ * D_ * 4;
  float*    h2   = (float*)p;    p += (size_t)ROWS_ * D_ * 4;
  ushort_t* h1hi = (ushort_t*)p; p += (size_t)ROWS_ * D_ * 2;
  ushort_t* h1lo = (ushort_t*)p; p += (size_t)ROWS_ * D_ * 2;
  ushort_t* h2hi = (ushort_t*)p; p += (size_t)ROWS_ * D_ * 2;
  ushort_t* h2lo = (ushort_t*)p; p += (size_t)ROWS_ * D_ * 2;
  int*      nbr  = (int*)p;      p += (size_t)ROWS_ * 32 * 4;
  float2*   mz   = (float2*)p;   p += (size_t)B_ * 2 * L_ * 4 * sizeof(float2);

  k_mlp<<<ROWS_ / 8, 256, 0, stream>>>(xin, lnin_g, lnin_b, w_in, b_in,
                                       lnh1_g, lnh1_b, w_h, b_h, lnh2_g, lnh2_b,
                                       h1, h1hi, h1lo);
  k_topk<<<ROWS_ / 4, 256, 0, stream>>>(dist, masks, nbr);
  k_stats<<<2048, 256, 0, stream>>>(h1hi, h1lo, masks, mz);
  k_gather<<<ROWS_ / 4, 256, 0, stream>>>(h1, nbr, mz, masks, lna0_g, lna0_b, 0,
                                          h2, h2hi, h2lo, w_out, b_out, y);
  k_stats<<<2048, 256, 0, stream>>>(h2hi, h2lo, masks, mz);
  k_gather<<<ROWS_ / 4, 256, 0, stream>>>(h2, nbr, mz, masks, lna1_g, lna1_b, 1,
                                          h2, h2hi, h2lo, w_out, b_out, y);
}